// Round 1
// baseline (9305.168 us; speedup 1.0000x reference)
//
#include <hip/hip_runtime.h>
#include <hip/hip_bf16.h>

// GRU: B=64 T=512 I=512 H=1024 M=8
// Partition: 4 teams (16 batch rows each) x 64 WGs (16 H-cols each).
// Per WG: waves 0..2 = gates z/r/n (full-K MFMA GEMMs, Wh slice resident in
// LDS in B-frag order, Wx slice pre-swizzled in global), wave 3 = mode-head
// reduce/softmax for step t-1. Team barrier = device-scope atomic counter.
// h carried fp32 in WG-private LDS; bf16 only for matmul operands.

typedef __attribute__((ext_vector_type(8))) short short8_t;
typedef __attribute__((ext_vector_type(4))) float float4_t;

#define T_STEPS 512

// workspace layout (bytes)
#define OFF_XBF  0ull
#define SZ_XBF   (64ull*512*512*2)            // 33,554,432
#define OFF_WH   (OFF_XBF + SZ_XBF)
#define SZ_WH    (64ull*3*32*64*8*2)          // 6,291,456
#define OFF_WX   (OFF_WH + SZ_WH)
#define SZ_WX    (64ull*3*16*64*8*2)          // 3,145,728
#define OFF_HBUF (OFF_WX + SZ_WX)
#define SZ_HBUF  (2ull*64*1024*2)             // 262,144
#define OFF_PART (OFF_HBUF + SZ_HBUF)
#define SZ_PART  (3ull*4*64*16*8*4)           // 393,216
#define OFF_CTR  (OFF_PART + SZ_PART)
#define SZ_CTR   4096ull

// output layout (fp32 elements)
#define HN_OFF   (64ull*512*1024)             // 33,554,432
#define MP_OFF   (HN_OFF + 64ull*1024)        // 33,619,968

#define SMEM_BYTES (98304 + 4096 + 1024 + 512)  // whlds + cz/cr/chn/cxn + hloc + wmlds

static __device__ __forceinline__ unsigned short f2bf(float f) {
    __hip_bfloat16 h = __float2bfloat16(f);
    unsigned short u;
    __builtin_memcpy(&u, &h, 2);
    return u;
}

// ---- prep kernels ----------------------------------------------------------

__global__ void prep_x(const float* __restrict__ x, unsigned short* __restrict__ xbf) {
    const size_t i = ((size_t)blockIdx.x * 256 + threadIdx.x) * 4;   // grid covers exactly 16,777,216
    const float4 v = *(const float4*)(x + i);
    ushort4 o = make_ushort4(f2bf(v.x), f2bf(v.y), f2bf(v.z), f2bf(v.w));
    *(ushort4*)(xbf + i) = o;
}

__global__ void prep_h0(const float* __restrict__ h0, unsigned short* __restrict__ hbuf) {
    const size_t i = ((size_t)blockIdx.x * 256 + threadIdx.x) * 4;   // 65,536 elems
    const float4 v = *(const float4*)(h0 + i);
    ushort4 o = make_ushort4(f2bf(v.x), f2bf(v.y), f2bf(v.z), f2bf(v.w));
    *(ushort4*)(hbuf + i) = o;
}

// whswz[((twg*3+g)*32+kt)*64+lane][j] = Wh[kt*32+(lane>>4)*8+j][g*1024+twg*16+(lane&15)]
__global__ void prep_wh_k(const float* __restrict__ Wh, unsigned short* __restrict__ whswz) {
    const int tid = blockIdx.x * 256 + threadIdx.x;   // 393,216 total
    const int lane = tid & 63;
    const int r = tid >> 6;
    const int kt = r & 31;
    const int r2 = r >> 5;            // twg*3+g, 0..191
    const int g = r2 % 3;
    const int twg = r2 / 3;
    const int col = g * 1024 + twg * 16 + (lane & 15);
    const int k0 = kt * 32 + (lane >> 4) * 8;
    unsigned short tmp[8];
#pragma unroll
    for (int j = 0; j < 8; ++j) tmp[j] = f2bf(Wh[(size_t)(k0 + j) * 3072 + col]);
    ushort4* dst = (ushort4*)(whswz + (size_t)tid * 8);
    dst[0] = make_ushort4(tmp[0], tmp[1], tmp[2], tmp[3]);
    dst[1] = make_ushort4(tmp[4], tmp[5], tmp[6], tmp[7]);
}

__global__ void prep_wx_k(const float* __restrict__ Wx, unsigned short* __restrict__ wxswz) {
    const int tid = blockIdx.x * 256 + threadIdx.x;   // 196,608 total
    const int lane = tid & 63;
    const int r = tid >> 6;
    const int kt = r & 15;
    const int r2 = r >> 4;            // twg*3+g
    const int g = r2 % 3;
    const int twg = r2 / 3;
    const int col = g * 1024 + twg * 16 + (lane & 15);
    const int k0 = kt * 32 + (lane >> 4) * 8;
    unsigned short tmp[8];
#pragma unroll
    for (int j = 0; j < 8; ++j) tmp[j] = f2bf(Wx[(size_t)(k0 + j) * 3072 + col]);
    ushort4* dst = (ushort4*)(wxswz + (size_t)tid * 8);
    dst[0] = make_ushort4(tmp[0], tmp[1], tmp[2], tmp[3]);
    dst[1] = make_ushort4(tmp[4], tmp[5], tmp[6], tmp[7]);
}

// ---- persistent GRU kernel -------------------------------------------------

__global__ void __launch_bounds__(256, 1) gru_persistent(
    const unsigned short* __restrict__ xbf,
    const unsigned short* __restrict__ whswz,
    const unsigned short* __restrict__ wxswz,
    unsigned short* __restrict__ hbuf,
    float* __restrict__ part,
    unsigned int* __restrict__ ctr,
    const float* __restrict__ h0,
    const float* __restrict__ bvec,
    const float* __restrict__ wm,
    const float* __restrict__ bm,
    float* __restrict__ out)
{
    extern __shared__ char smem[];
    unsigned short* whlds = (unsigned short*)smem;          // 49,152 ushorts
    float* cz    = (float*)(smem + 98304);                  // [16][16]
    float* cr    = cz + 256;
    float* chn   = cr + 256;
    float* cxn   = chn + 256;
    float* hloc  = cxn + 256;                               // [16][16] fp32 h (WG-private slice)
    float* wmlds = hloc + 256;                              // [16][8]

    const int wg   = blockIdx.x;
    const int team = wg & 3;          // blockIdx%4 -> teams interleave XCDs
    const int twg  = wg >> 2;         // 0..63: H-col slice owner
    const int tid  = threadIdx.x;
    const int wave = tid >> 6;
    const int lane = tid & 63;
    const int quad = lane >> 4;
    const int lrow = lane & 15;
    const int b0   = team * 16;
    const int colg = twg * 16 + (tid & 15);

    // one-time LDS setup
    {
        const uint4* src = (const uint4*)(whswz + (size_t)twg * 49152);
        uint4* dst = (uint4*)whlds;
        for (int i = tid; i < 6144; i += 256) dst[i] = src[i];
    }
    if (tid < 128) wmlds[tid] = wm[(twg * 16 + (tid >> 3)) * 8 + (tid & 7)];
    hloc[tid] = h0[(size_t)(b0 + (tid >> 4)) * 1024 + colg];
    const float bz = bvec[colg], br = bvec[1024 + colg], bn = bvec[2048 + colg];
    __syncthreads();

    unsigned int* myctr = ctr + team * 64;   // 256-B spaced counters
    const int g = wave;                       // gate id for waves 0..2

    auto mp_reduce = [&](int tprev) {
        const int p = tprev % 3;
        const int row = twg;                  // caller guards twg<16
        const float* pp = part + ((size_t)p * 4 + team) * 8192 + (size_t)lane * 128 + row * 8;
        float4 va = *(const float4*)pp;
        float4 vb = *(const float4*)(pp + 4);
#pragma unroll
        for (int off = 1; off < 64; off <<= 1) {
            va.x += __shfl_xor(va.x, off); va.y += __shfl_xor(va.y, off);
            va.z += __shfl_xor(va.z, off); va.w += __shfl_xor(va.w, off);
            vb.x += __shfl_xor(vb.x, off); vb.y += __shfl_xor(vb.y, off);
            vb.z += __shfl_xor(vb.z, off); vb.w += __shfl_xor(vb.w, off);
        }
        if (lane == 0) {
            float v[8] = {va.x, va.y, va.z, va.w, vb.x, vb.y, vb.z, vb.w};
            float mx = -3.4e38f;
#pragma unroll
            for (int m = 0; m < 8; ++m) { v[m] += bm[m]; mx = fmaxf(mx, v[m]); }
            float s = 0.f;
#pragma unroll
            for (int m = 0; m < 8; ++m) { v[m] = expf(v[m] - mx); s += v[m]; }
            const float inv = 1.f / s;
            float* dst = out + MP_OFF + ((size_t)(b0 + row) * 512 + tprev) * 8;
#pragma unroll
            for (int m = 0; m < 8; ++m) dst[m] = v[m] * inv;
        }
    };

    for (int t = 0; t < T_STEPS; ++t) {
        float4_t acc0 = {0.f,0.f,0.f,0.f}, acc1 = {0.f,0.f,0.f,0.f};
        float4_t xacc0 = {0.f,0.f,0.f,0.f}, xacc1 = {0.f,0.f,0.f,0.f};

        // x-GEMM (h-independent) BEFORE the barrier wait — hides sync latency
        if (wave < 3) {
            const unsigned short* xrow = xbf + ((size_t)(b0 + lrow) * 512 + t) * 512 + quad * 8;
            const unsigned short* wxb  = wxswz + ((size_t)(twg * 3 + g) * 16 * 64 + lane) * 8;
#pragma unroll
            for (int kt = 0; kt < 16; kt += 2) {
                short8_t a0 = *(const short8_t*)(xrow + kt * 32);
                short8_t a1 = *(const short8_t*)(xrow + kt * 32 + 32);
                short8_t w0 = *(const short8_t*)(wxb + (size_t)kt * 512);
                short8_t w1 = *(const short8_t*)(wxb + (size_t)kt * 512 + 512);
                xacc0 = __builtin_amdgcn_mfma_f32_16x16x32_bf16(a0, w0, xacc0, 0, 0, 0);
                xacc1 = __builtin_amdgcn_mfma_f32_16x16x32_bf16(a1, w1, xacc1, 0, 0, 0);
            }
        }

        // team barrier wait: h_t visible after all team WGs arrived t times
        if (tid == 0 && t > 0) {
            const unsigned int tgt = 64u * (unsigned)t;
            while (__hip_atomic_load(myctr, __ATOMIC_RELAXED, __HIP_MEMORY_SCOPE_AGENT) < tgt)
                __builtin_amdgcn_s_sleep(1);
            __threadfence();
        }
        __syncthreads();

        if (wave < 3) {
            // h-GEMM from bf16 hbuf + LDS-resident B-frags
            const unsigned short* hrow = hbuf + (size_t)(t & 1) * 65536 + (size_t)(b0 + lrow) * 1024 + quad * 8;
            const unsigned short* whb  = whlds + ((size_t)g * 32 * 64 + lane) * 8;
#pragma unroll
            for (int kt = 0; kt < 32; kt += 2) {
                short8_t a0 = *(const short8_t*)(hrow + kt * 32);
                short8_t a1 = *(const short8_t*)(hrow + kt * 32 + 32);
                short8_t w0 = *(const short8_t*)(whb + (size_t)kt * 512);
                short8_t w1 = *(const short8_t*)(whb + (size_t)kt * 512 + 512);
                acc0 = __builtin_amdgcn_mfma_f32_16x16x32_bf16(a0, w0, acc0, 0, 0, 0);
                acc1 = __builtin_amdgcn_mfma_f32_16x16x32_bf16(a1, w1, acc1, 0, 0, 0);
            }
            float4_t cv  = acc0 + acc1;     // h contribution
            float4_t cxv = xacc0 + xacc1;   // x contribution
            if (g < 2) {
                float* cd = (g == 0) ? cz : cr;
                cv += cxv;                  // z,r: gx+gh merge OK
#pragma unroll
                for (int rg = 0; rg < 4; ++rg) cd[(quad * 4 + rg) * 16 + lrow] = cv[rg];
            } else {
                // n gate: keep hn and xn separate (r multiplies hn only)
#pragma unroll
                for (int rg = 0; rg < 4; ++rg) {
                    chn[(quad * 4 + rg) * 16 + lrow] = cv[rg];
                    cxn[(quad * 4 + rg) * 16 + lrow] = cxv[rg];
                }
            }
        } else {
            if (t > 0 && twg < 16) mp_reduce(t - 1);   // overlapped with h-GEMM
        }
        __syncthreads();

        // gate update: thread owns (row=tid>>4, col=tid&15)
        {
            const int urow = tid >> 4;
            float zz = cz[tid] + bz;
            float rr = cr[tid] + br;
            zz = 1.f / (1.f + expf(-zz));
            rr = 1.f / (1.f + expf(-rr));
            const float nn = tanhf(cxn[tid] + bn + rr * chn[tid]);
            const float hold = hloc[tid];
            const float hnew = hold + zz * (nn - hold);
            hloc[tid] = hnew;
            hbuf[(size_t)((t + 1) & 1) * 65536 + (size_t)(b0 + urow) * 1024 + colg] = f2bf(hnew);
            out[((size_t)(b0 + urow) * 512 + t) * 1024 + colg] = hnew;
        }
        __syncthreads();

        // mode-head partial for this step (reads full hloc)
        if (tid < 128) {
            const int prow = tid >> 3, pm = tid & 7;
            float s = 0.f;
#pragma unroll
            for (int c = 0; c < 16; ++c) s += hloc[prow * 16 + c] * wmlds[c * 8 + pm];
            part[((size_t)(t % 3) * 4 + team) * 8192 + (size_t)twg * 128 + prow * 8 + pm] = s;
        }
        __syncthreads();   // drains each thread's vm ops before arrive

        if (tid == 0) {
            __threadfence();
            __hip_atomic_fetch_add(myctr, 1u, __ATOMIC_RELEASE, __HIP_MEMORY_SCOPE_AGENT);
        }
    }

    // tail: wait for team completion, then h_n + final mode probs
    if (tid == 0) {
        while (__hip_atomic_load(myctr, __ATOMIC_RELAXED, __HIP_MEMORY_SCOPE_AGENT) < 64u * (unsigned)T_STEPS)
            __builtin_amdgcn_s_sleep(1);
        __threadfence();
    }
    __syncthreads();
    out[HN_OFF + (size_t)(b0 + (tid >> 4)) * 1024 + colg] = hloc[tid];
    if (wave == 3 && twg < 16) mp_reduce(T_STEPS - 1);
}

// ---- host ------------------------------------------------------------------

extern "C" void kernel_launch(void* const* d_in, const int* in_sizes, int n_in,
                              void* d_out, int out_size, void* d_ws, size_t ws_size,
                              hipStream_t stream) {
    (void)in_sizes; (void)n_in; (void)out_size; (void)ws_size;
    const float* input = (const float*)d_in[0];
    const float* h0    = (const float*)d_in[1];
    const float* Wx    = (const float*)d_in[2];
    const float* Wh    = (const float*)d_in[3];
    const float* bvec  = (const float*)d_in[4];
    const float* Wm    = (const float*)d_in[5];
    const float* bm    = (const float*)d_in[6];
    float* out = (float*)d_out;

    char* ws = (char*)d_ws;
    unsigned short* xbf   = (unsigned short*)(ws + OFF_XBF);
    unsigned short* whswz = (unsigned short*)(ws + OFF_WH);
    unsigned short* wxswz = (unsigned short*)(ws + OFF_WX);
    unsigned short* hbuf  = (unsigned short*)(ws + OFF_HBUF);
    float*          partb = (float*)(ws + OFF_PART);
    unsigned int*   ctr   = (unsigned int*)(ws + OFF_CTR);

    hipMemsetAsync(ws + OFF_CTR, 0, SZ_CTR, stream);

    prep_x   <<<16384, 256, 0, stream>>>(input, xbf);
    prep_h0  <<<64,    256, 0, stream>>>(h0, hbuf);
    prep_wh_k<<<1536,  256, 0, stream>>>(Wh, whswz);
    prep_wx_k<<<768,   256, 0, stream>>>(Wx, wxswz);

    hipFuncSetAttribute((const void*)gru_persistent,
                        hipFuncAttributeMaxDynamicSharedMemorySize, SMEM_BYTES);

    void* args[] = {&xbf, &whswz, &wxswz, &hbuf, &partb, &ctr,
                    (void*)&h0, (void*)&bvec, (void*)&Wm, (void*)&bm, &out};
    hipLaunchCooperativeKernel((void*)gru_persistent, dim3(256), dim3(256),
                               args, (unsigned)SMEM_BYTES, stream);
}

// Round 2
// 7877.961 us; speedup vs baseline: 1.1812x; 1.1812x over previous
//
#include <hip/hip_runtime.h>
#include <hip/hip_bf16.h>

// GRU: B=64 T=512 I=512 H=1024 M=8
// Partition: 4 teams (16 batch rows each) x 64 WGs (16 H-cols each).
// Per WG: waves 0..2 = gates z/r/n (full-K MFMA GEMMs, Wh slice resident in
// LDS in B-frag order, Wx slice pre-swizzled in global), wave 3 = mode-head
// reduce/softmax for step t-1.
// R1 change: team barrier was ONE fetch_add counter per team -> 64 serialized
// cross-XCD RMWs ~18us/step. Now: per-WG flag array (uncontended relaxed
// atomic store) + wave-0 parallel poll (64 lanes x 1 flag each, coalesced).
// h carried fp32 in WG-private LDS; bf16 only for matmul operands.

typedef __attribute__((ext_vector_type(8))) short short8_t;
typedef __attribute__((ext_vector_type(4))) float float4_t;

#define T_STEPS 512

// workspace layout (bytes)
#define OFF_XBF  0ull
#define SZ_XBF   (64ull*512*512*2)            // 33,554,432
#define OFF_WH   (OFF_XBF + SZ_XBF)
#define SZ_WH    (64ull*3*32*64*8*2)          // 6,291,456
#define OFF_WX   (OFF_WH + SZ_WH)
#define SZ_WX    (64ull*3*16*64*8*2)          // 3,145,728
#define OFF_HBUF (OFF_WX + SZ_WX)
#define SZ_HBUF  (2ull*64*1024*2)             // 262,144
#define OFF_PART (OFF_HBUF + SZ_HBUF)
#define SZ_PART  (3ull*4*64*16*8*4)           // 393,216
#define OFF_CTR  (OFF_PART + SZ_PART)
#define SZ_CTR   4096ull                      // flag array: [4 teams][64 wgs] u32

// output layout (fp32 elements)
#define HN_OFF   (64ull*512*1024)             // 33,554,432
#define MP_OFF   (HN_OFF + 64ull*1024)        // 33,619,968

#define SMEM_BYTES (98304 + 4096 + 1024 + 512)  // whlds + cz/cr/chn/cxn + hloc + wmlds

static __device__ __forceinline__ unsigned short f2bf(float f) {
    __hip_bfloat16 h = __float2bfloat16(f);
    unsigned short u;
    __builtin_memcpy(&u, &h, 2);
    return u;
}

// ---- prep kernels ----------------------------------------------------------

__global__ void prep_x(const float* __restrict__ x, unsigned short* __restrict__ xbf) {
    const size_t i = ((size_t)blockIdx.x * 256 + threadIdx.x) * 4;   // grid covers exactly 16,777,216
    const float4 v = *(const float4*)(x + i);
    ushort4 o = make_ushort4(f2bf(v.x), f2bf(v.y), f2bf(v.z), f2bf(v.w));
    *(ushort4*)(xbf + i) = o;
}

__global__ void prep_h0(const float* __restrict__ h0, unsigned short* __restrict__ hbuf) {
    const size_t i = ((size_t)blockIdx.x * 256 + threadIdx.x) * 4;   // 65,536 elems
    const float4 v = *(const float4*)(h0 + i);
    ushort4 o = make_ushort4(f2bf(v.x), f2bf(v.y), f2bf(v.z), f2bf(v.w));
    *(ushort4*)(hbuf + i) = o;
}

// whswz[((twg*3+g)*32+kt)*64+lane][j] = Wh[kt*32+(lane>>4)*8+j][g*1024+twg*16+(lane&15)]
__global__ void prep_wh_k(const float* __restrict__ Wh, unsigned short* __restrict__ whswz) {
    const int tid = blockIdx.x * 256 + threadIdx.x;   // 393,216 total
    const int lane = tid & 63;
    const int r = tid >> 6;
    const int kt = r & 31;
    const int r2 = r >> 5;            // twg*3+g, 0..191
    const int g = r2 % 3;
    const int twg = r2 / 3;
    const int col = g * 1024 + twg * 16 + (lane & 15);
    const int k0 = kt * 32 + (lane >> 4) * 8;
    unsigned short tmp[8];
#pragma unroll
    for (int j = 0; j < 8; ++j) tmp[j] = f2bf(Wh[(size_t)(k0 + j) * 3072 + col]);
    ushort4* dst = (ushort4*)(whswz + (size_t)tid * 8);
    dst[0] = make_ushort4(tmp[0], tmp[1], tmp[2], tmp[3]);
    dst[1] = make_ushort4(tmp[4], tmp[5], tmp[6], tmp[7]);
}

__global__ void prep_wx_k(const float* __restrict__ Wx, unsigned short* __restrict__ wxswz) {
    const int tid = blockIdx.x * 256 + threadIdx.x;   // 196,608 total
    const int lane = tid & 63;
    const int r = tid >> 6;
    const int kt = r & 15;
    const int r2 = r >> 4;            // twg*3+g
    const int g = r2 % 3;
    const int twg = r2 / 3;
    const int col = g * 1024 + twg * 16 + (lane & 15);
    const int k0 = kt * 32 + (lane >> 4) * 8;
    unsigned short tmp[8];
#pragma unroll
    for (int j = 0; j < 8; ++j) tmp[j] = f2bf(Wx[(size_t)(k0 + j) * 3072 + col]);
    ushort4* dst = (ushort4*)(wxswz + (size_t)tid * 8);
    dst[0] = make_ushort4(tmp[0], tmp[1], tmp[2], tmp[3]);
    dst[1] = make_ushort4(tmp[4], tmp[5], tmp[6], tmp[7]);
}

// ---- persistent GRU kernel -------------------------------------------------

__global__ void __launch_bounds__(256, 1) gru_persistent(
    const unsigned short* __restrict__ xbf,
    const unsigned short* __restrict__ whswz,
    const unsigned short* __restrict__ wxswz,
    unsigned short* __restrict__ hbuf,
    float* __restrict__ part,
    unsigned int* __restrict__ flags,
    const float* __restrict__ h0,
    const float* __restrict__ bvec,
    const float* __restrict__ wm,
    const float* __restrict__ bm,
    float* __restrict__ out)
{
    extern __shared__ char smem[];
    unsigned short* whlds = (unsigned short*)smem;          // 49,152 ushorts
    float* cz    = (float*)(smem + 98304);                  // [16][16]
    float* cr    = cz + 256;
    float* chn   = cr + 256;
    float* cxn   = chn + 256;
    float* hloc  = cxn + 256;                               // [16][16] fp32 h (WG-private slice)
    float* wmlds = hloc + 256;                               // [16][8]

    const int wg   = blockIdx.x;
    const int team = wg & 3;          // blockIdx%4 -> teams interleave XCDs
    const int twg  = wg >> 2;         // 0..63: H-col slice owner
    const int tid  = threadIdx.x;
    const int wave = tid >> 6;
    const int lane = tid & 63;
    const int quad = lane >> 4;
    const int lrow = lane & 15;
    const int b0   = team * 16;
    const int colg = twg * 16 + (tid & 15);

    // one-time LDS setup
    {
        const uint4* src = (const uint4*)(whswz + (size_t)twg * 49152);
        uint4* dst = (uint4*)whlds;
        for (int i = tid; i < 6144; i += 256) dst[i] = src[i];
    }
    if (tid < 128) wmlds[tid] = wm[(twg * 16 + (tid >> 3)) * 8 + (tid & 7)];
    hloc[tid] = h0[(size_t)(b0 + (tid >> 4)) * 1024 + colg];
    const float bz = bvec[colg], br = bvec[1024 + colg], bn = bvec[2048 + colg];
    __syncthreads();

    unsigned int* teamflags = flags + team * 64;   // 256B contiguous per team
    unsigned int* myflag    = teamflags + twg;
    const int g = wave;                            // gate id for waves 0..2

    auto mp_reduce = [&](int tprev) {
        const int p = tprev % 3;
        const int row = twg;                  // caller guards twg<16
        const float* pp = part + ((size_t)p * 4 + team) * 8192 + (size_t)lane * 128 + row * 8;
        float4 va = *(const float4*)pp;
        float4 vb = *(const float4*)(pp + 4);
#pragma unroll
        for (int off = 1; off < 64; off <<= 1) {
            va.x += __shfl_xor(va.x, off); va.y += __shfl_xor(va.y, off);
            va.z += __shfl_xor(va.z, off); va.w += __shfl_xor(va.w, off);
            vb.x += __shfl_xor(vb.x, off); vb.y += __shfl_xor(vb.y, off);
            vb.z += __shfl_xor(vb.z, off); vb.w += __shfl_xor(vb.w, off);
        }
        if (lane == 0) {
            float v[8] = {va.x, va.y, va.z, va.w, vb.x, vb.y, vb.z, vb.w};
            float mx = -3.4e38f;
#pragma unroll
            for (int m = 0; m < 8; ++m) { v[m] += bm[m]; mx = fmaxf(mx, v[m]); }
            float s = 0.f;
#pragma unroll
            for (int m = 0; m < 8; ++m) { v[m] = expf(v[m] - mx); s += v[m]; }
            const float inv = 1.f / s;
            float* dst = out + MP_OFF + ((size_t)(b0 + row) * 512 + tprev) * 8;
#pragma unroll
            for (int m = 0; m < 8; ++m) dst[m] = v[m] * inv;
        }
    };

    for (int t = 0; t < T_STEPS; ++t) {
        float4_t acc0 = {0.f,0.f,0.f,0.f}, acc1 = {0.f,0.f,0.f,0.f};
        float4_t xacc0 = {0.f,0.f,0.f,0.f}, xacc1 = {0.f,0.f,0.f,0.f};

        // x-GEMM (h-independent) BEFORE the barrier wait — hides sync latency
        if (wave < 3) {
            const unsigned short* xrow = xbf + ((size_t)(b0 + lrow) * 512 + t) * 512 + quad * 8;
            const unsigned short* wxb  = wxswz + ((size_t)(twg * 3 + g) * 16 * 64 + lane) * 8;
#pragma unroll
            for (int kt = 0; kt < 16; kt += 2) {
                short8_t a0 = *(const short8_t*)(xrow + kt * 32);
                short8_t a1 = *(const short8_t*)(xrow + kt * 32 + 32);
                short8_t w0 = *(const short8_t*)(wxb + (size_t)kt * 512);
                short8_t w1 = *(const short8_t*)(wxb + (size_t)kt * 512 + 512);
                xacc0 = __builtin_amdgcn_mfma_f32_16x16x32_bf16(a0, w0, xacc0, 0, 0, 0);
                xacc1 = __builtin_amdgcn_mfma_f32_16x16x32_bf16(a1, w1, xacc1, 0, 0, 0);
            }
        }

        // team barrier wait: wave 0's lanes poll the 64 per-WG flags in parallel
        if (t > 0 && wave == 0) {
            const unsigned int tgt = (unsigned)t;
            while (__hip_atomic_load(teamflags + lane, __ATOMIC_RELAXED,
                                     __HIP_MEMORY_SCOPE_AGENT) < tgt) { }
            __threadfence();   // acquire: invalidate L1(+stale L2) before reading hbuf
        }
        __syncthreads();

        if (wave < 3) {
            // h-GEMM from bf16 hbuf + LDS-resident B-frags
            const unsigned short* hrow = hbuf + (size_t)(t & 1) * 65536 + (size_t)(b0 + lrow) * 1024 + quad * 8;
            const unsigned short* whb  = whlds + ((size_t)g * 32 * 64 + lane) * 8;
#pragma unroll
            for (int kt = 0; kt < 32; kt += 2) {
                short8_t a0 = *(const short8_t*)(hrow + kt * 32);
                short8_t a1 = *(const short8_t*)(hrow + kt * 32 + 32);
                short8_t w0 = *(const short8_t*)(whb + (size_t)kt * 512);
                short8_t w1 = *(const short8_t*)(whb + (size_t)kt * 512 + 512);
                acc0 = __builtin_amdgcn_mfma_f32_16x16x32_bf16(a0, w0, acc0, 0, 0, 0);
                acc1 = __builtin_amdgcn_mfma_f32_16x16x32_bf16(a1, w1, acc1, 0, 0, 0);
            }
            float4_t cv  = acc0 + acc1;     // h contribution
            float4_t cxv = xacc0 + xacc1;   // x contribution
            if (g < 2) {
                float* cd = (g == 0) ? cz : cr;
                cv += cxv;                  // z,r: gx+gh merge OK
#pragma unroll
                for (int rg = 0; rg < 4; ++rg) cd[(quad * 4 + rg) * 16 + lrow] = cv[rg];
            } else {
                // n gate: keep hn and xn separate (r multiplies hn only)
#pragma unroll
                for (int rg = 0; rg < 4; ++rg) {
                    chn[(quad * 4 + rg) * 16 + lrow] = cv[rg];
                    cxn[(quad * 4 + rg) * 16 + lrow] = cxv[rg];
                }
            }
        } else {
            if (t > 0 && twg < 16) mp_reduce(t - 1);   // overlapped with h-GEMM
        }
        __syncthreads();

        // gate update: thread owns (row=tid>>4, col=tid&15)
        {
            const int urow = tid >> 4;
            float zz = cz[tid] + bz;
            float rr = cr[tid] + br;
            zz = 1.f / (1.f + expf(-zz));
            rr = 1.f / (1.f + expf(-rr));
            const float nn = tanhf(cxn[tid] + bn + rr * chn[tid]);
            const float hold = hloc[tid];
            const float hnew = hold + zz * (nn - hold);
            hloc[tid] = hnew;
            hbuf[(size_t)((t + 1) & 1) * 65536 + (size_t)(b0 + urow) * 1024 + colg] = f2bf(hnew);
            out[((size_t)(b0 + urow) * 512 + t) * 1024 + colg] = hnew;
        }
        __syncthreads();

        // mode-head partial for this step (reads full hloc)
        if (tid < 128) {
            const int prow = tid >> 3, pm = tid & 7;
            float s = 0.f;
#pragma unroll
            for (int c = 0; c < 16; ++c) s += hloc[prow * 16 + c] * wmlds[c * 8 + pm];
            part[((size_t)(t % 3) * 4 + team) * 8192 + (size_t)twg * 128 + prow * 8 + pm] = s;
        }
        __syncthreads();   // all threads' stores issued before arrival signal

        if (tid == 0) {
            __threadfence();   // release: write back dirty L2 so team (cross-XCD) sees hbuf
            __hip_atomic_store(myflag, (unsigned)(t + 1), __ATOMIC_RELAXED,
                               __HIP_MEMORY_SCOPE_AGENT);
        }
    }

    // tail: wait for team completion, then h_n + final mode probs
    if (wave == 0) {
        while (__hip_atomic_load(teamflags + lane, __ATOMIC_RELAXED,
                                 __HIP_MEMORY_SCOPE_AGENT) < (unsigned)T_STEPS) { }
        __threadfence();
    }
    __syncthreads();
    out[HN_OFF + (size_t)(b0 + (tid >> 4)) * 1024 + colg] = hloc[tid];
    if (wave == 3 && twg < 16) mp_reduce(T_STEPS - 1);
}

// ---- host ------------------------------------------------------------------

extern "C" void kernel_launch(void* const* d_in, const int* in_sizes, int n_in,
                              void* d_out, int out_size, void* d_ws, size_t ws_size,
                              hipStream_t stream) {
    (void)in_sizes; (void)n_in; (void)out_size; (void)ws_size;
    const float* input = (const float*)d_in[0];
    const float* h0    = (const float*)d_in[1];
    const float* Wx    = (const float*)d_in[2];
    const float* Wh    = (const float*)d_in[3];
    const float* bvec  = (const float*)d_in[4];
    const float* Wm    = (const float*)d_in[5];
    const float* bm    = (const float*)d_in[6];
    float* out = (float*)d_out;

    char* ws = (char*)d_ws;
    unsigned short* xbf   = (unsigned short*)(ws + OFF_XBF);
    unsigned short* whswz = (unsigned short*)(ws + OFF_WH);
    unsigned short* wxswz = (unsigned short*)(ws + OFF_WX);
    unsigned short* hbuf  = (unsigned short*)(ws + OFF_HBUF);
    float*          partb = (float*)(ws + OFF_PART);
    unsigned int*   flagp = (unsigned int*)(ws + OFF_CTR);

    hipMemsetAsync(ws + OFF_CTR, 0, SZ_CTR, stream);

    prep_x   <<<16384, 256, 0, stream>>>(input, xbf);
    prep_h0  <<<64,    256, 0, stream>>>(h0, hbuf);
    prep_wh_k<<<1536,  256, 0, stream>>>(Wh, whswz);
    prep_wx_k<<<768,   256, 0, stream>>>(Wx, wxswz);

    hipFuncSetAttribute((const void*)gru_persistent,
                        hipFuncAttributeMaxDynamicSharedMemorySize, SMEM_BYTES);

    void* args[] = {&xbf, &whswz, &wxswz, &hbuf, &partb, &flagp,
                    (void*)&h0, (void*)&bvec, (void*)&Wm, (void*)&bm, &out};
    hipLaunchCooperativeKernel((void*)gru_persistent, dim3(256), dim3(256),
                               args, (unsigned)SMEM_BYTES, stream);
}

// Round 3
// 4701.207 us; speedup vs baseline: 1.9793x; 1.6757x over previous
//
#include <hip/hip_runtime.h>
#include <hip/hip_bf16.h>

// GRU: B=64 T=512 I=512 H=1024 M=8
// Partition: 4 teams (16 batch rows each) x 64 WGs (16 H-cols each).
// R2 change: __threadfence() (agent release/acquire) emits buffer_wbl2/buffer_inv
// = full L2 tag-walks, ~15us/step on the critical path. Eliminated: ALL cross-WG
// data (hbuf, part) now moves via agent-scope RELAXED atomics (sc0|sc1, bypass
// L1/L2, coherent at LLC). __syncthreads' vmcnt(0) drain + relaxed flag store
// gives release semantics with no fence. hbuf is staged once per WG into padded
// LDS (dedupe 3 gate waves: 96->32 KB/WG/step of LLC reads), frags via ds_read_b128.

typedef __attribute__((ext_vector_type(8))) short short8_t;
typedef __attribute__((ext_vector_type(4))) float float4_t;

#define T_STEPS 512

// workspace layout (bytes)
#define OFF_XBF  0ull
#define SZ_XBF   (64ull*512*512*2)            // 33,554,432
#define OFF_WH   (OFF_XBF + SZ_XBF)
#define SZ_WH    (64ull*3*32*64*8*2)          // 6,291,456
#define OFF_WX   (OFF_WH + SZ_WH)
#define SZ_WX    (64ull*3*16*64*8*2)          // 3,145,728
#define OFF_HBUF (OFF_WX + SZ_WX)
#define SZ_HBUF  (2ull*64*1024*2)             // 262,144 (2 x [64][512] u32)
#define OFF_PART (OFF_HBUF + SZ_HBUF)
#define SZ_PART  (3ull*4*64*16*8*4)           // 393,216
#define OFF_CTR  (OFF_PART + SZ_PART)
#define SZ_CTR   4096ull                      // flag array: [4 teams][64 wgs] u32

// output layout (fp32 elements)
#define HN_OFF   (64ull*512*1024)             // 33,554,432
#define MP_OFF   (HN_OFF + 64ull*1024)        // 33,619,968

// LDS: whlds 98304 | cz/cr/chn/cxn 4096 | hloc 1024 | wmlds 512 | hlds 16*2064
#define HLDS_STRIDE 2064                      // 1032 shorts: breaks bank alias
#define SMEM_BYTES (98304 + 4096 + 1024 + 512 + 16*HLDS_STRIDE)

static __device__ __forceinline__ unsigned short f2bf(float f) {
    __hip_bfloat16 h = __float2bfloat16(f);
    unsigned short u;
    __builtin_memcpy(&u, &h, 2);
    return u;
}
static __device__ __forceinline__ void st_agent_u32(unsigned* p, unsigned v) {
    __hip_atomic_store(p, v, __ATOMIC_RELAXED, __HIP_MEMORY_SCOPE_AGENT);
}
static __device__ __forceinline__ void st_agent_u64(unsigned long long* p, unsigned long long v) {
    __hip_atomic_store(p, v, __ATOMIC_RELAXED, __HIP_MEMORY_SCOPE_AGENT);
}
static __device__ __forceinline__ unsigned long long ld_agent_u64(const unsigned long long* p) {
    return __hip_atomic_load(p, __ATOMIC_RELAXED, __HIP_MEMORY_SCOPE_AGENT);
}

// ---- prep kernels ----------------------------------------------------------

__global__ void prep_x(const float* __restrict__ x, unsigned short* __restrict__ xbf) {
    const size_t i = ((size_t)blockIdx.x * 256 + threadIdx.x) * 4;
    const float4 v = *(const float4*)(x + i);
    ushort4 o = make_ushort4(f2bf(v.x), f2bf(v.y), f2bf(v.z), f2bf(v.w));
    *(ushort4*)(xbf + i) = o;
}

__global__ void prep_h0(const float* __restrict__ h0, unsigned short* __restrict__ hbuf) {
    const size_t i = ((size_t)blockIdx.x * 256 + threadIdx.x) * 4;   // 65,536 elems
    const float4 v = *(const float4*)(h0 + i);
    ushort4 o = make_ushort4(f2bf(v.x), f2bf(v.y), f2bf(v.z), f2bf(v.w));
    *(ushort4*)(hbuf + i) = o;
}

// whswz[((twg*3+g)*32+kt)*64+lane][j] = Wh[kt*32+(lane>>4)*8+j][g*1024+twg*16+(lane&15)]
__global__ void prep_wh_k(const float* __restrict__ Wh, unsigned short* __restrict__ whswz) {
    const int tid = blockIdx.x * 256 + threadIdx.x;   // 393,216 total
    const int lane = tid & 63;
    const int r = tid >> 6;
    const int kt = r & 31;
    const int r2 = r >> 5;            // twg*3+g
    const int g = r2 % 3;
    const int twg = r2 / 3;
    const int col = g * 1024 + twg * 16 + (lane & 15);
    const int k0 = kt * 32 + (lane >> 4) * 8;
    unsigned short tmp[8];
#pragma unroll
    for (int j = 0; j < 8; ++j) tmp[j] = f2bf(Wh[(size_t)(k0 + j) * 3072 + col]);
    ushort4* dst = (ushort4*)(whswz + (size_t)tid * 8);
    dst[0] = make_ushort4(tmp[0], tmp[1], tmp[2], tmp[3]);
    dst[1] = make_ushort4(tmp[4], tmp[5], tmp[6], tmp[7]);
}

__global__ void prep_wx_k(const float* __restrict__ Wx, unsigned short* __restrict__ wxswz) {
    const int tid = blockIdx.x * 256 + threadIdx.x;   // 196,608 total
    const int lane = tid & 63;
    const int r = tid >> 6;
    const int kt = r & 15;
    const int r2 = r >> 4;            // twg*3+g
    const int g = r2 % 3;
    const int twg = r2 / 3;
    const int col = g * 1024 + twg * 16 + (lane & 15);
    const int k0 = kt * 32 + (lane >> 4) * 8;
    unsigned short tmp[8];
#pragma unroll
    for (int j = 0; j < 8; ++j) tmp[j] = f2bf(Wx[(size_t)(k0 + j) * 3072 + col]);
    ushort4* dst = (ushort4*)(wxswz + (size_t)tid * 8);
    dst[0] = make_ushort4(tmp[0], tmp[1], tmp[2], tmp[3]);
    dst[1] = make_ushort4(tmp[4], tmp[5], tmp[6], tmp[7]);
}

// ---- persistent GRU kernel -------------------------------------------------

__global__ void __launch_bounds__(256, 1) gru_persistent(
    const unsigned short* __restrict__ xbf,
    const unsigned short* __restrict__ whswz,
    const unsigned short* __restrict__ wxswz,
    unsigned* __restrict__ hbuf32,
    unsigned long long* __restrict__ part64,
    unsigned int* __restrict__ flags,
    const float* __restrict__ h0,
    const float* __restrict__ bvec,
    const float* __restrict__ wm,
    const float* __restrict__ bm,
    float* __restrict__ out)
{
    extern __shared__ char smem[];
    unsigned short* whlds = (unsigned short*)smem;          // 49,152 ushorts
    float* cz    = (float*)(smem + 98304);                  // [16][16]
    float* cr    = cz + 256;
    float* chn   = cr + 256;
    float* cxn   = chn + 256;
    float* hloc  = cxn + 256;                               // [16][16] fp32 h slice
    float* wmlds = hloc + 256;                              // [16][8]
    char*  hlds  = smem + 98304 + 4096 + 1024 + 512;        // 16 rows x HLDS_STRIDE

    const int wg   = blockIdx.x;
    const int team = wg & 3;
    const int twg  = wg >> 2;
    const int tid  = threadIdx.x;
    const int wave = tid >> 6;
    const int lane = tid & 63;
    const int quad = lane >> 4;
    const int lrow = lane & 15;
    const int b0   = team * 16;
    const int colg = twg * 16 + (tid & 15);

    // one-time LDS setup
    {
        const uint4* src = (const uint4*)(whswz + (size_t)twg * 49152);
        uint4* dst = (uint4*)whlds;
        for (int i = tid; i < 6144; i += 256) dst[i] = src[i];
    }
    if (tid < 128) wmlds[tid] = wm[(twg * 16 + (tid >> 3)) * 8 + (tid & 7)];
    hloc[tid] = h0[(size_t)(b0 + (tid >> 4)) * 1024 + colg];
    const float bz = bvec[colg], br = bvec[1024 + colg], bn = bvec[2048 + colg];
    __syncthreads();

    unsigned int* teamflags = flags + team * 64;
    unsigned int* myflag    = teamflags + twg;
    const int g = wave;                            // gate id for waves 0..2

    auto mp_reduce = [&](int tprev) {
        const int p = tprev % 3;
        const int row = twg;                  // caller guards twg<16
        const unsigned long long* pp = part64 + ((size_t)p * 4 + team) * 4096 + (size_t)lane * 64 + row * 4;
        unsigned long long q0 = ld_agent_u64(pp + 0);
        unsigned long long q1 = ld_agent_u64(pp + 1);
        unsigned long long q2 = ld_agent_u64(pp + 2);
        unsigned long long q3 = ld_agent_u64(pp + 3);
        float4 va, vb;
        va.x = __uint_as_float((unsigned)q0); va.y = __uint_as_float((unsigned)(q0 >> 32));
        va.z = __uint_as_float((unsigned)q1); va.w = __uint_as_float((unsigned)(q1 >> 32));
        vb.x = __uint_as_float((unsigned)q2); vb.y = __uint_as_float((unsigned)(q2 >> 32));
        vb.z = __uint_as_float((unsigned)q3); vb.w = __uint_as_float((unsigned)(q3 >> 32));
#pragma unroll
        for (int off = 1; off < 64; off <<= 1) {
            va.x += __shfl_xor(va.x, off); va.y += __shfl_xor(va.y, off);
            va.z += __shfl_xor(va.z, off); va.w += __shfl_xor(va.w, off);
            vb.x += __shfl_xor(vb.x, off); vb.y += __shfl_xor(vb.y, off);
            vb.z += __shfl_xor(vb.z, off); vb.w += __shfl_xor(vb.w, off);
        }
        if (lane == 0) {
            float v[8] = {va.x, va.y, va.z, va.w, vb.x, vb.y, vb.z, vb.w};
            float mx = -3.4e38f;
#pragma unroll
            for (int m = 0; m < 8; ++m) { v[m] += bm[m]; mx = fmaxf(mx, v[m]); }
            float s = 0.f;
#pragma unroll
            for (int m = 0; m < 8; ++m) { v[m] = expf(v[m] - mx); s += v[m]; }
            const float inv = 1.f / s;
            float* dst = out + MP_OFF + ((size_t)(b0 + row) * 512 + tprev) * 8;
#pragma unroll
            for (int m = 0; m < 8; ++m) dst[m] = v[m] * inv;
        }
    };

    for (int t = 0; t < T_STEPS; ++t) {
        float4_t acc0 = {0.f,0.f,0.f,0.f}, acc1 = {0.f,0.f,0.f,0.f};
        float4_t xacc0 = {0.f,0.f,0.f,0.f}, xacc1 = {0.f,0.f,0.f,0.f};

        // x-GEMM (h-independent) BEFORE the barrier wait — hides sync latency
        if (wave < 3) {
            const unsigned short* xrow = xbf + ((size_t)(b0 + lrow) * 512 + t) * 512 + quad * 8;
            const unsigned short* wxb  = wxswz + ((size_t)(twg * 3 + g) * 16 * 64 + lane) * 8;
#pragma unroll
            for (int kt = 0; kt < 16; kt += 2) {
                short8_t a0 = *(const short8_t*)(xrow + kt * 32);
                short8_t a1 = *(const short8_t*)(xrow + kt * 32 + 32);
                short8_t w0 = *(const short8_t*)(wxb + (size_t)kt * 512);
                short8_t w1 = *(const short8_t*)(wxb + (size_t)kt * 512 + 512);
                xacc0 = __builtin_amdgcn_mfma_f32_16x16x32_bf16(a0, w0, xacc0, 0, 0, 0);
                xacc1 = __builtin_amdgcn_mfma_f32_16x16x32_bf16(a1, w1, xacc1, 0, 0, 0);
            }
        }

        // team barrier wait: wave 0's lanes poll the 64 per-WG flags in parallel
        if (t > 0 && wave == 0) {
            const unsigned int tgt = (unsigned)t;
            while (__hip_atomic_load(teamflags + lane, __ATOMIC_RELAXED,
                                     __HIP_MEMORY_SCOPE_AGENT) < tgt) { }
        }
        __syncthreads();

        // stage this team's h slice (16 rows x 512 u32) into LDS via LLC-direct loads
        {
            const unsigned long long* hsrc =
                (const unsigned long long*)(hbuf32 + (size_t)(t & 1) * 32768) + (size_t)b0 * 256;
#pragma unroll
            for (int i = 0; i < 16; ++i) {
                const int d = tid + i * 256;        // 0..4095
                const int r = d >> 8, c = d & 255;  // row, u64-within-row
                unsigned long long v = ld_agent_u64(hsrc + (size_t)r * 256 + c);
                *(unsigned long long*)(hlds + r * HLDS_STRIDE + c * 8) = v;
            }
        }
        __syncthreads();

        if (wave < 3) {
            // h-GEMM: A-frags from padded LDS, B-frags LDS-resident
            const char* hrowp = hlds + lrow * HLDS_STRIDE + quad * 16;
            const unsigned short* whb = whlds + ((size_t)g * 32 * 64 + lane) * 8;
#pragma unroll
            for (int kt = 0; kt < 32; kt += 2) {
                short8_t a0 = *(const short8_t*)(hrowp + kt * 64);
                short8_t a1 = *(const short8_t*)(hrowp + kt * 64 + 64);
                short8_t w0 = *(const short8_t*)(whb + (size_t)kt * 512);
                short8_t w1 = *(const short8_t*)(whb + (size_t)kt * 512 + 512);
                acc0 = __builtin_amdgcn_mfma_f32_16x16x32_bf16(a0, w0, acc0, 0, 0, 0);
                acc1 = __builtin_amdgcn_mfma_f32_16x16x32_bf16(a1, w1, acc1, 0, 0, 0);
            }
            float4_t cv  = acc0 + acc1;     // h contribution
            float4_t cxv = xacc0 + xacc1;   // x contribution
            if (g < 2) {
                float* cd = (g == 0) ? cz : cr;
                cv += cxv;
#pragma unroll
                for (int rg = 0; rg < 4; ++rg) cd[(quad * 4 + rg) * 16 + lrow] = cv[rg];
            } else {
#pragma unroll
                for (int rg = 0; rg < 4; ++rg) {
                    chn[(quad * 4 + rg) * 16 + lrow] = cv[rg];
                    cxn[(quad * 4 + rg) * 16 + lrow] = cxv[rg];
                }
            }
        } else {
            if (t > 0 && twg < 16) mp_reduce(t - 1);   // overlapped with h-GEMM
        }
        __syncthreads();

        // gate update: thread owns (row=tid>>4, col=tid&15)
        {
            const int urow = tid >> 4;
            float zz = cz[tid] + bz;
            float rr = cr[tid] + br;
            zz = 1.f / (1.f + expf(-zz));
            rr = 1.f / (1.f + expf(-rr));
            const float nn = tanhf(cxn[tid] + bn + rr * chn[tid]);
            const float hold = hloc[tid];
            const float hnew = hold + zz * (nn - hold);
            hloc[tid] = hnew;
            // pack bf16 pair with lane partner, even lane stores u32 (LLC-direct)
            const unsigned short hb = f2bf(hnew);
            const unsigned partner = (unsigned)__shfl_xor((int)hb, 1) & 0xffffu;
            if ((tid & 1) == 0) {
                const unsigned w = (unsigned)hb | (partner << 16);
                st_agent_u32(hbuf32 + (size_t)((t + 1) & 1) * 32768
                                   + (size_t)(b0 + urow) * 512 + (colg >> 1), w);
            }
            out[((size_t)(b0 + urow) * 512 + t) * 1024 + colg] = hnew;
        }
        __syncthreads();

        // mode-head partial (reads full hloc), pack float pair -> u64 LLC-direct
        if (tid < 128) {
            const int prow = tid >> 3, pm = tid & 7;
            float s = 0.f;
#pragma unroll
            for (int c = 0; c < 16; ++c) s += hloc[prow * 16 + c] * wmlds[c * 8 + pm];
            const unsigned sb = __float_as_uint(s);
            const unsigned pother = (unsigned)__shfl_xor((int)sb, 1);
            if ((tid & 1) == 0) {
                const unsigned long long w = (unsigned long long)sb
                                           | ((unsigned long long)pother << 32);
                st_agent_u64(part64 + ((size_t)(t % 3) * 4 + team) * 4096
                                    + (size_t)twg * 64 + prow * 4 + (pm >> 1), w);
            }
        }
        __syncthreads();   // vmcnt(0) drain: all sc1 stores LLC-visible before signal

        if (tid == 0) {
            __hip_atomic_store(myflag, (unsigned)(t + 1), __ATOMIC_RELAXED,
                               __HIP_MEMORY_SCOPE_AGENT);
        }
    }

    // tail: wait for team completion, then h_n + final mode probs
    if (wave == 0) {
        while (__hip_atomic_load(teamflags + lane, __ATOMIC_RELAXED,
                                 __HIP_MEMORY_SCOPE_AGENT) < (unsigned)T_STEPS) { }
    }
    __syncthreads();
    out[HN_OFF + (size_t)(b0 + (tid >> 4)) * 1024 + colg] = hloc[tid];
    if (wave == 3 && twg < 16) mp_reduce(T_STEPS - 1);
}

// ---- host ------------------------------------------------------------------

extern "C" void kernel_launch(void* const* d_in, const int* in_sizes, int n_in,
                              void* d_out, int out_size, void* d_ws, size_t ws_size,
                              hipStream_t stream) {
    (void)in_sizes; (void)n_in; (void)out_size; (void)ws_size;
    const float* input = (const float*)d_in[0];
    const float* h0    = (const float*)d_in[1];
    const float* Wx    = (const float*)d_in[2];
    const float* Wh    = (const float*)d_in[3];
    const float* bvec  = (const float*)d_in[4];
    const float* Wm    = (const float*)d_in[5];
    const float* bm    = (const float*)d_in[6];
    float* out = (float*)d_out;

    char* ws = (char*)d_ws;
    unsigned short* xbf   = (unsigned short*)(ws + OFF_XBF);
    unsigned short* whswz = (unsigned short*)(ws + OFF_WH);
    unsigned short* wxswz = (unsigned short*)(ws + OFF_WX);
    unsigned*       hbuf32= (unsigned*)(ws + OFF_HBUF);
    unsigned long long* part64 = (unsigned long long*)(ws + OFF_PART);
    unsigned int*   flagp = (unsigned int*)(ws + OFF_CTR);

    hipMemsetAsync(ws + OFF_CTR, 0, SZ_CTR, stream);

    prep_x   <<<16384, 256, 0, stream>>>(input, xbf);
    prep_h0  <<<64,    256, 0, stream>>>(h0, (unsigned short*)(ws + OFF_HBUF));
    prep_wh_k<<<1536,  256, 0, stream>>>(Wh, whswz);
    prep_wx_k<<<768,   256, 0, stream>>>(Wx, wxswz);

    hipFuncSetAttribute((const void*)gru_persistent,
                        hipFuncAttributeMaxDynamicSharedMemorySize, SMEM_BYTES);

    void* args[] = {&xbf, &whswz, &wxswz, &hbuf32, &part64, &flagp,
                    (void*)&h0, (void*)&bvec, (void*)&Wm, (void*)&bm, &out};
    hipLaunchCooperativeKernel((void*)gru_persistent, dim3(256), dim3(256),
                               args, (unsigned)SMEM_BYTES, stream);
}